// Round 5
// baseline (5013.877 us; speedup 1.0000x reference)
//
#include <hip/hip_runtime.h>
#include <hip/hip_bf16.h>

// Problem constants (B,C,H,W) = (8,256,128,128), fp32 everywhere.
#define BB 8
#define CC 256
#define HH 128
#define WW 128
#define HW (HH*WW)        // 16384
#define NPIX (BB*HW)      // 131072

// ---------------------------------------------------------------------------
// conf = clip(1 - beta*sigmoid(20*sigmoid(x) - 4), 0, 1); also zero GN stats.
// ---------------------------------------------------------------------------
__global__ __launch_bounds__(256) void k_conf(const float* __restrict__ bl,
                                              const float* __restrict__ beta,
                                              float* __restrict__ conf,
                                              float* __restrict__ stats) {
  const int t = threadIdx.x;
  if (blockIdx.x == 0) { stats[t] = 0.f; stats[t + 256] = 0.f; }
  const int i = blockIdx.x * 256 + t;
  float x = bl[i];
  float s1 = 1.f / (1.f + expf(-x));
  float s2 = 1.f / (1.f + expf(-(20.f * s1 - 4.f)));
  float cv = 1.f - beta[0] * s2;
  conf[i] = fminf(fmaxf(cv, 0.f), 1.f);
}

// ---------------------------------------------------------------------------
// Transpose the 4 W_in matrices + out_w into [c_in][c_out].
// ---------------------------------------------------------------------------
__global__ __launch_bounds__(256) void k_tr(const float* __restrict__ W_in,
                                            const float* __restrict__ out_w,
                                            float* __restrict__ wT) {
  const int i = blockIdx.x * 256 + threadIdx.x;   // 0 .. 5*65536
  const int m = i >> 16;
  const int rr = i & 65535;
  const int c = rr >> 8;
  const int d = rr & 255;
  const float* src = (m < 4) ? (W_in + m * 65536) : out_w;
  wT[i] = src[d * 256 + c];
}

// ---------------------------------------------------------------------------
// proj[dir] = W_in[dir] @ feature (per pixel) + b_in[dir]
// Register tile: thread = (ch-quad q = t&63, px-group p = t>>6 of 16 px).
// ---------------------------------------------------------------------------
__global__ __launch_bounds__(256) void k_proj_gemm(const float* __restrict__ feature,
                                                   const float* __restrict__ wT,
                                                   const float* __restrict__ bias,
                                                   float* __restrict__ proj,
                                                   int vertical) {
  __shared__ float Xs[256 * 64];   // [c][px], 64 KiB
  const int t = threadIdx.x;
  const int b = blockIdx.y;
  const int p0 = blockIdx.x * 64;

  {
    const int j = t & 63, c0 = t >> 6;
#pragma unroll
    for (int cc = 0; cc < 64; ++cc) {
      int c = cc * 4 + c0;
      Xs[c * 64 + j] = feature[((b * CC + c) << 14) + p0 + j];
    }
  }
  __syncthreads();

  const int q = t & 63;     // ch quad: channels q*4..q*4+3
  const int p = t >> 6;     // px group: pixels p*16..p*16+15

  float acc[4][16];
#pragma unroll
  for (int ch = 0; ch < 4; ++ch)
#pragma unroll
    for (int px = 0; px < 16; ++px) acc[ch][px] = 0.f;

#pragma unroll 2
  for (int c = 0; c < 256; ++c) {
    const float4 w4 = *reinterpret_cast<const float4*>(wT + c * 256 + q * 4);
#pragma unroll
    for (int p4 = 0; p4 < 4; ++p4) {
      const float4 xv = *reinterpret_cast<const float4*>(&Xs[c * 64 + p * 16 + p4 * 4]);
      acc[0][p4 * 4 + 0] += w4.x * xv.x; acc[0][p4 * 4 + 1] += w4.x * xv.y;
      acc[0][p4 * 4 + 2] += w4.x * xv.z; acc[0][p4 * 4 + 3] += w4.x * xv.w;
      acc[1][p4 * 4 + 0] += w4.y * xv.x; acc[1][p4 * 4 + 1] += w4.y * xv.y;
      acc[1][p4 * 4 + 2] += w4.y * xv.z; acc[1][p4 * 4 + 3] += w4.y * xv.w;
      acc[2][p4 * 4 + 0] += w4.z * xv.x; acc[2][p4 * 4 + 1] += w4.z * xv.y;
      acc[2][p4 * 4 + 2] += w4.z * xv.z; acc[2][p4 * 4 + 3] += w4.z * xv.w;
      acc[3][p4 * 4 + 0] += w4.w * xv.x; acc[3][p4 * 4 + 1] += w4.w * xv.y;
      acc[3][p4 * 4 + 2] += w4.w * xv.z; acc[3][p4 * 4 + 3] += w4.w * xv.w;
    }
  }

  const float4 bia = *reinterpret_cast<const float4*>(bias + q * 4);
#pragma unroll
  for (int jj = 0; jj < 16; ++jj) {
    const int pp = p0 + p * 16 + jj;
    const int pos = vertical ? (((pp & 127) << 7) + (pp >> 7)) : pp;
    float4 o = make_float4(acc[0][jj] + bia.x, acc[1][jj] + bia.y,
                           acc[2][jj] + bia.z, acc[3][jj] + bia.w);
    *reinterpret_cast<float4*>(&proj[(size_t)(b * HW + pos) * 256 + q * 4]) = o;
  }
}

// ---------------------------------------------------------------------------
// Gated scan, XOR-slot reduce-scatter edition.
// 1024 thr = 64 rowblocks (rbg) x 16 colgroups (g); 4 seqs/block.
// Thread's dt slot j = (k<<2)|r' holds the partial of OUTPUT j^g, realized by
// load-time permutation: weight slot r' <- row rbg*4+(r'^(g&3)) (global idx),
// LDS h read slot k <- seq k^(g>>2) (LDS addr). Fold levels then need NO
// cndmask: dt[j] += shfl_xor(dt[j+m], m) with static register indices.
// __launch_bounds__(1024,4): 128-VGPR cap -> no AGPR round-trips (round-4 bug:
// default cap 60 VGPR sent W/dt to AGPRs, ~3x VALU). 1 barrier/step.
// ---------------------------------------------------------------------------
__global__ __launch_bounds__(1024, 4) void k_scan(const float* __restrict__ proj,
                                                  const float* __restrict__ conf,
                                                  const float* __restrict__ Ws,
                                                  const float* __restrict__ b_s,
                                                  const float* __restrict__ p_bias,
                                                  float* __restrict__ accum,
                                                  int vertical, int rev, int first) {
  __shared__ __align__(16) float hbuf[2][4][CC];   // 8 KiB
  const int t = threadIdx.x;
  const int g = t & 15;         // colgroup (16 cols)
  const int rbg = t >> 4;       // rowblock (4 rows)
  const int grow = g & 3;       // row-permutation key
  const int gseq = g >> 2;      // seq-permutation key
  const int s_own = g >> 2;     // owned seq (output o = g)
  const int row = rbg * 4 + grow;      // owned output row

  // weight slots: Wq[r'][q] = W_s[rbg*4 + (r'^grow)][g*16 + ((q+(g>>1))&3)*4 ..]
  float4 Wq[4][4];
#pragma unroll
  for (int rp = 0; rp < 4; ++rp) {
    const float* wr = Ws + (rbg * 4 + (rp ^ grow)) * CC + g * 16;
#pragma unroll
    for (int q = 0; q < 4; ++q) {
      const int cq = (q + (g >> 1)) & 3;
      Wq[rp][q] = *reinterpret_cast<const float4*>(wr + cq * 4);
    }
  }
  const float cst = b_s[row] + p_bias[row];

  // per-slot LDS seq offsets (static index k, runtime value)
  int seqoff[4];
#pragma unroll
  for (int k = 0; k < 4; ++k) seqoff[k] = (k ^ gseq) * CC;
  int coloff[4];
#pragma unroll
  for (int q = 0; q < 4; ++q) coloff[q] = g * 16 + (((q + (g >> 1)) & 3) << 2);

  ((float*)hbuf)[t] = 0.f;   // zero buffer 0 (first 1024 floats)

  const int dp = rev ? -CC : CC;
  const int dc = vertical ? (rev ? -WW : WW) : (rev ? -1 : 1);
  const int da = vertical ? (rev ? -(WW * CC) : (WW * CC)) : dp;
  const int pstart = rev ? 127 : 0;

  const int n = blockIdx.x * 4 + s_own;
  int pix, cix, aix;
  if (!vertical) {
    pix = (n * WW + pstart) * CC + row;
    cix = n * WW + pstart;
    aix = pix;
  } else {
    pix = (n * HH + pstart) * CC + row;
    cix = (n >> 7) * HW + pstart * WW + (n & 127);
    aix = ((n >> 7) * HW + pstart * WW + (n & 127)) * CC + row;
  }

  float pj = proj[pix];
  float gg = conf[cix];
  float ard = first ? 0.f : accum[aix];
  pix += dp; cix += dc;
  __syncthreads();

  for (int kk = 0; kk < 128; ++kk) {
    float pjn = 0.f, ggn = 0.f, arn = 0.f;
    if (kk < 127) {
      pjn = proj[pix];
      ggn = conf[cix];
      if (!first) arn = accum[aix + da];
    }

    float dt[16];
#pragma unroll
    for (int v = 0; v < 16; ++v) dt[v] = 0.f;

    const float* hb = &hbuf[kk & 1][0][0];
#pragma unroll
    for (int q = 0; q < 4; ++q) {
      float4 hv[4];
#pragma unroll
      for (int k = 0; k < 4; ++k)
        hv[k] = *reinterpret_cast<const float4*>(hb + seqoff[k] + coloff[q]);
#pragma unroll
      for (int k = 0; k < 4; ++k)
#pragma unroll
        for (int rp = 0; rp < 4; ++rp) {
          dt[k * 4 + rp] += Wq[rp][q].x * hv[k].x + Wq[rp][q].y * hv[k].y +
                            Wq[rp][q].z * hv[k].z + Wq[rp][q].w * hv[k].w;
        }
    }

    // XOR-slot reduce-scatter: no selects, static indices throughout.
#pragma unroll
    for (int j = 0; j < 8; ++j) dt[j] += __shfl_xor(dt[j + 8], 8);
#pragma unroll
    for (int j = 0; j < 4; ++j) dt[j] += __shfl_xor(dt[j + 4], 4);
#pragma unroll
    for (int j = 0; j < 2; ++j) dt[j] += __shfl_xor(dt[j + 2], 2);
    dt[0] += __shfl_xor(dt[1], 1);

    // uniform epilogue: lane g owns output g = (seq s_own, row)
    const float hn = fmaxf(pj + gg * dt[0] + cst, 0.f);
    hbuf[(kk + 1) & 1][s_own][row] = hn;
    accum[aix] = first ? hn : (hn + ard);
    aix += da;
    pj = pjn; gg = ggn; ard = arn;
    pix += dp; cix += dc;
    __syncthreads();
  }
}

// ---------------------------------------------------------------------------
// z = out_w @ fused + out_b + feature ; GN partial sums per (b, group).
// ---------------------------------------------------------------------------
__global__ __launch_bounds__(256) void k_out_gemm(const float* __restrict__ fused,
                                                  const float* __restrict__ owT,
                                                  const float* __restrict__ out_b,
                                                  const float* __restrict__ feature,
                                                  float* __restrict__ out,
                                                  float* __restrict__ stats) {
  __shared__ float Fs[256 * 64];   // [c][px]
  const int t = threadIdx.x;
  const int b = blockIdx.y;
  const int p0 = blockIdx.x * 64;

  {
    const int px = t >> 2, cq = t & 3;
    const float* src = fused + ((size_t)(b * HW + p0 + px)) * 256 + cq * 64;
#pragma unroll
    for (int kk = 0; kk < 16; ++kk) {
      float4 v = *reinterpret_cast<const float4*>(src + kk * 4);
      int c = cq * 64 + kk * 4;
      Fs[(c + 0) * 64 + px] = v.x; Fs[(c + 1) * 64 + px] = v.y;
      Fs[(c + 2) * 64 + px] = v.z; Fs[(c + 3) * 64 + px] = v.w;
    }
  }
  __syncthreads();

  const int pq = t & 15;    // px quad: pixels pq*4..+3
  const int cg = t >> 4;    // ch group: channels cg*16..+15

  float acc[16][4];
#pragma unroll
  for (int ch = 0; ch < 16; ++ch)
#pragma unroll
    for (int px = 0; px < 4; ++px) acc[ch][px] = 0.f;

#pragma unroll 2
  for (int c = 0; c < 256; ++c) {
    const float4 xv = *reinterpret_cast<const float4*>(&Fs[c * 64 + pq * 4]);
#pragma unroll
    for (int wi = 0; wi < 4; ++wi) {
      const float4 w4 = *reinterpret_cast<const float4*>(owT + c * 256 + cg * 16 + wi * 4);
      acc[wi * 4 + 0][0] += w4.x * xv.x; acc[wi * 4 + 0][1] += w4.x * xv.y;
      acc[wi * 4 + 0][2] += w4.x * xv.z; acc[wi * 4 + 0][3] += w4.x * xv.w;
      acc[wi * 4 + 1][0] += w4.y * xv.x; acc[wi * 4 + 1][1] += w4.y * xv.y;
      acc[wi * 4 + 1][2] += w4.y * xv.z; acc[wi * 4 + 1][3] += w4.y * xv.w;
      acc[wi * 4 + 2][0] += w4.z * xv.x; acc[wi * 4 + 2][1] += w4.z * xv.y;
      acc[wi * 4 + 2][2] += w4.z * xv.z; acc[wi * 4 + 2][3] += w4.z * xv.w;
      acc[wi * 4 + 3][0] += w4.w * xv.x; acc[wi * 4 + 3][1] += w4.w * xv.y;
      acc[wi * 4 + 3][2] += w4.w * xv.z; acc[wi * 4 + 3][3] += w4.w * xv.w;
    }
  }

  float s1a = 0.f, s2a = 0.f, s1b = 0.f, s2b = 0.f;
#pragma unroll
  for (int ch = 0; ch < 16; ++ch) {
    const int cabs = cg * 16 + ch;
    const float bia = out_b[cabs];
    const size_t base = ((size_t)(b * 256 + cabs) << 14) + p0 + pq * 4;
    const float4 f = *reinterpret_cast<const float4*>(feature + base);
    float4 z = make_float4(acc[ch][0] + bia + f.x, acc[ch][1] + bia + f.y,
                           acc[ch][2] + bia + f.z, acc[ch][3] + bia + f.w);
    *reinterpret_cast<float4*>(&out[base]) = z;
    float ps = z.x + z.y + z.z + z.w;
    float pq2 = z.x * z.x + z.y * z.y + z.z * z.z + z.w * z.w;
    if (ch < 8) { s1a += ps; s2a += pq2; } else { s1b += ps; s2b += pq2; }
  }
#pragma unroll
  for (int m = 1; m <= 8; m <<= 1) {
    s1a += __shfl_xor(s1a, m); s2a += __shfl_xor(s2a, m);
    s1b += __shfl_xor(s1b, m); s2b += __shfl_xor(s2b, m);
  }
  if (pq == 0) {
    atomicAdd(&stats[(b * 32 + cg * 2 + 0) * 2 + 0], s1a);
    atomicAdd(&stats[(b * 32 + cg * 2 + 0) * 2 + 1], s2a);
    atomicAdd(&stats[(b * 32 + cg * 2 + 1) * 2 + 0], s1b);
    atomicAdd(&stats[(b * 32 + cg * 2 + 1) * 2 + 1], s2b);
  }
}

// ---------------------------------------------------------------------------
// In-place GroupNorm normalize of d_out using accumulated stats.
// ---------------------------------------------------------------------------
__global__ __launch_bounds__(256) void k_norm(float* __restrict__ out,
                                              const float* __restrict__ stats,
                                              const float* __restrict__ gn_w,
                                              const float* __restrict__ gn_b) {
  const int i = (blockIdx.x * 256 + threadIdx.x) << 2;
  const int c = (i >> 14) & 255;
  const int b = i >> 22;
  const int g = c >> 3;
  float s1 = stats[(b * 32 + g) * 2 + 0];
  float s2 = stats[(b * 32 + g) * 2 + 1];
  const float invN = 1.f / 131072.f;
  float mu = s1 * invN;
  float var = fmaxf(s2 * invN - mu * mu, 0.f);
  float is = rsqrtf(var + 1e-5f);
  float wmul = gn_w[c] * is;
  float badd = gn_b[c] - mu * wmul;
  float4 z = *reinterpret_cast<float4*>(&out[i]);
  z.x = z.x * wmul + badd; z.y = z.y * wmul + badd;
  z.z = z.z * wmul + badd; z.w = z.w * wmul + badd;
  *reinterpret_cast<float4*>(&out[i]) = z;
}

// ---------------------------------------------------------------------------
extern "C" void kernel_launch(void* const* d_in, const int* in_sizes, int n_in,
                              void* d_out, int out_size, void* d_ws, size_t ws_size,
                              hipStream_t stream) {
  const float* feature = (const float*)d_in[0];
  const float* blog    = (const float*)d_in[1];
  const float* beta    = (const float*)d_in[2];
  const float* W_in    = (const float*)d_in[3];
  const float* b_in    = (const float*)d_in[4];
  const float* W_s     = (const float*)d_in[5];
  const float* b_s     = (const float*)d_in[6];
  const float* p_bias  = (const float*)d_in[7];
  const float* out_w   = (const float*)d_in[8];
  const float* out_b   = (const float*)d_in[9];
  const float* gn_w    = (const float*)d_in[10];
  const float* gn_b    = (const float*)d_in[11];
  float* out = (float*)d_out;

  // workspace layout (floats): proj 33.5M | accum 33.5M | conf 128K | stats 512 | wT 320K
  float* ws    = (float*)d_ws;
  float* proj  = ws;
  float* accum = ws + 33554432;
  float* conf  = ws + 67108864;
  float* stats = ws + 67239936;
  float* wT    = ws + 67240448;    // 5 * 65536

  k_conf<<<NPIX / 256, 256, 0, stream>>>(blog, beta, conf, stats);
  k_tr<<<(5 * 65536) / 256, 256, 0, stream>>>(W_in, out_w, wT);

  for (int dir = 0; dir < 4; ++dir) {
    const int vertical = (dir >= 2);
    const int rev = (dir == 1 || dir == 3);
    k_proj_gemm<<<dim3(HW / 64, BB), 256, 0, stream>>>(
        feature, wT + dir * 65536, b_in + dir * 256, proj, vertical);
    k_scan<<<256, 1024, 0, stream>>>(
        proj, conf, W_s + dir * 65536, b_s + dir * 256, p_bias + dir * 256,
        accum, vertical, rev, dir == 0);
  }

  k_out_gemm<<<dim3(HW / 64, BB), 256, 0, stream>>>(
      accum, wT + 4 * 65536, out_b, feature, out, stats);
  k_norm<<<(BB * CC * HW) / 1024, 256, 0, stream>>>(out, stats, gn_w, gn_b);
}